// Round 1
// baseline (150.410 us; speedup 1.0000x reference)
//
#include <hip/hip_runtime.h>

#define V_IN 40962
#define V_OUT 163842
#define NCH 64
#define CTOT 256

// ---------------- transpose: x[2][256][V_IN] -> xT[2][V_IN][256] ----------------
__global__ __launch_bounds__(256) void transpose_k(const float* __restrict__ x,
                                                   float* __restrict__ xT) {
    __shared__ float tile[32][33];
    const int b  = blockIdx.z;
    const int v0 = blockIdx.x * 32;
    const int c0 = blockIdx.y * 32;
    const int tx = threadIdx.x;   // 0..31
    const int ty = threadIdx.y;   // 0..7
#pragma unroll
    for (int k = 0; k < 4; ++k) {
        int c = c0 + ty + 8 * k;
        int v = v0 + tx;
        float val = 0.0f;
        if (v < V_IN) val = x[((size_t)b * CTOT + c) * V_IN + v];
        tile[ty + 8 * k][tx] = val;
    }
    __syncthreads();
#pragma unroll
    for (int k = 0; k < 4; ++k) {
        int v = v0 + ty + 8 * k;
        int c = c0 + tx;
        if (v < V_IN) xT[((size_t)b * V_IN + v) * CTOT + c] = tile[tx][ty + 8 * k];
    }
}

// ---------------- fused gather + attn + softmax + weighted sum ----------------
// DIRECT=0: xsrc is xT[b][v_in][256] (channel-contiguous, coalesced float4 gathers)
// DIRECT=1: xsrc is original x[b][ch][V_IN] (fallback, strided gathers)
template <int DIRECT>
__global__ __launch_bounds__(256) void fused_k(const float* __restrict__ xsrc,
                                               const float* __restrict__ coeffs,
                                               const int* __restrict__ map,
                                               float* __restrict__ out) {
    __shared__ float otile[2][NCH][65];   // pad 65: write-phase lanes hit 2-way banks (free)
    __shared__ int   jmap[128];

    const int tid   = threadIdx.x;
    const int lane  = tid & 63;
    const int w     = tid >> 6;      // wave 0..3
    const int b     = w >> 1;        // batch handled by this wave
    const int vbase = blockIdx.x * 64;

    if (tid < 128) {
        int gi = vbase * 2 + tid;
        jmap[tid] = (gi < 2 * V_OUT) ? map[gi] : 0;
    }

    // lane-uniform loads -> expect SGPRs; no pre-scaling (no scalar FP mul on CDNA)
    float cs[64];
#pragma unroll
    for (int k = 0; k < 64; ++k) cs[k] = coeffs[k];

    __syncthreads();

    const int c = lane;  // channel group 0..63
    for (int i = 0; i < 32; ++i) {
        const int vl = (w & 1) + 2 * i;   // this wave's v within tile
        const int v  = vbase + vl;
        float r = 0.0f;
        if (v < V_OUT) {
            const int j0 = jmap[2 * vl];
            const int j1 = jmap[2 * vl + 1];
            float vals[8];  // k = e*2 + d
            if (DIRECT) {
#pragma unroll
                for (int e = 0; e < 4; ++e) {
                    vals[2 * e]     = xsrc[((size_t)b * CTOT + 4 * c + e) * V_IN + j0];
                    vals[2 * e + 1] = xsrc[((size_t)b * CTOT + 4 * c + e) * V_IN + j1];
                }
            } else {
                const float4 a0 = *((const float4*)(xsrc + ((size_t)b * V_IN + j0) * CTOT) + c);
                const float4 a1 = *((const float4*)(xsrc + ((size_t)b * V_IN + j1) * CTOT) + c);
                vals[0] = a0.x; vals[1] = a1.x; vals[2] = a0.y; vals[3] = a1.y;
                vals[4] = a0.z; vals[5] = a1.z; vals[6] = a0.w; vals[7] = a1.w;
            }
            // attn[f] = sum_k vals[k] * coeffs[k][f]
            float s[8];
#pragma unroll
            for (int f = 0; f < 8; ++f) {
                float acc = vals[0] * cs[f];
#pragma unroll
                for (int k = 1; k < 8; ++k) acc = fmaf(vals[k], cs[k * 8 + f], acc);
                s[f] = acc;
            }
            float m = s[0];
#pragma unroll
            for (int f = 1; f < 8; ++f) m = fmaxf(m, s[f]);
            float sum = 0.0f, num = 0.0f;
#pragma unroll
            for (int f = 0; f < 8; ++f) {
                float e = __expf((s[f] - m) * 0.125f);  // /8 temperature folded here
                sum += e;
                num = fmaf(vals[f], e, num);            // unnormalized weighted sum
            }
            r = num / sum;
        }
        otile[b][c][vl] = r;
    }
    __syncthreads();

    // coalesced write-out: rows are (b,c), 64 consecutive v each
    if (vbase + 64 <= V_OUT) {
#pragma unroll 1
        for (int rr = 2 * w; rr < 128; rr += 8) {
            int r  = rr + (lane >> 5);
            int bb = r >> 6, cc = r & 63;
            int vv = (lane & 31) * 2;
            float2 val;
            val.x = otile[bb][cc][vv];
            val.y = otile[bb][cc][vv + 1];
            *(float2*)(out + ((size_t)bb * NCH + cc) * V_OUT + vbase + vv) = val;
        }
    } else {
        for (int rr = w; rr < 128; rr += 4) {
            int bb = rr >> 6, cc = rr & 63;
            int v  = vbase + lane;
            if (v < V_OUT) out[((size_t)bb * NCH + cc) * V_OUT + v] = otile[bb][cc][lane];
        }
    }
}

extern "C" void kernel_launch(void* const* d_in, const int* in_sizes, int n_in,
                              void* d_out, int out_size, void* d_ws, size_t ws_size,
                              hipStream_t stream) {
    const float* x      = (const float*)d_in[0];
    const float* coeffs = (const float*)d_in[1];
    const int*   map    = (const int*)d_in[2];
    float*       out    = (float*)d_out;

    const size_t xT_bytes = (size_t)2 * V_IN * CTOT * sizeof(float);
    const int nblocks = (V_OUT + 63) / 64;

    if (ws_size >= xT_bytes) {
        float* xT = (float*)d_ws;
        dim3 tgrid((V_IN + 31) / 32, CTOT / 32, 2);
        transpose_k<<<tgrid, dim3(32, 8), 0, stream>>>(x, xT);
        fused_k<0><<<nblocks, 256, 0, stream>>>(xT, coeffs, map, out);
    } else {
        fused_k<1><<<nblocks, 256, 0, stream>>>(x, coeffs, map, out);
    }
}